// Round 8
// baseline (348.565 us; speedup 1.0000x reference)
//
#include <hip/hip_runtime.h>
#include <math.h>

#define NB 256
#define NV 32000
#define ND 1024
#define NT 64

// ---- GEMM config ----
#define GN 64
#define BSTR 40            // B row stride (f16): [h x16][q x16][pad x8]; 80B rows, 16B-aligned
#define NKB 64             // 16-wide k-blocks in A3
#define NK2 32             // 32-wide iteration count
#define AKBF 8192          // f16 per 16-k block, fragment order
#define NGBLK (NV / GN)    // 500
#define INV2048F 4.8828125e-4f

// ---- sampling config ----
#define NBIN 1024
#define HSTR 1032
#define HTOT (4 * HSTR)
#define FIX2 4294967296.0
#define SMASK ((1ull << 48) - 1ull)
#define SMEM_BYTES (NV * 4 + HTOT * 4)  // 144512 B

typedef _Float16 f16x8 __attribute__((ext_vector_type(8)));
typedef _Float16 f16x4 __attribute__((ext_vector_type(4)));
typedef float f32x16 __attribute__((ext_vector_type(16)));

struct RowP2 {
  unsigned long long basePack;
  unsigned long long toppZfix;
  unsigned pfx;
  int ktop;
  float invZ;
  unsigned ustar;
  int m;
  int cEq;
};

__device__ __forceinline__ unsigned mono_enc(float f) {
  unsigned u = __float_as_uint(f);
  return (u & 0x80000000u) ? ~u : (u | 0x80000000u);
}
__device__ __forceinline__ float mono_dec(unsigned u) {
  return (u & 0x80000000u) ? __uint_as_float(u & 0x7FFFFFFFu) : __uint_as_float(~u);
}

// ---------------- convert A: write MFMA-fragment-ordered h/q planes (unchanged R7) --
__global__ __launch_bounds__(256) void convert_A(const float* __restrict__ hidden,
                                                 _Float16* __restrict__ A3) {
  const int g = blockIdx.x * 256 + threadIdx.x;   // 65536 total
  const int kb = g >> 10, rem = g & 1023, r = rem >> 2, c = rem & 3;
  const float4 a4 = *(const float4*)(hidden + (size_t)r * ND + kb * 16 + c * 4);
  const float v[4] = {a4.x, a4.y, a4.z, a4.w};
  f16x4 h4, q4;
#pragma unroll
  for (int q = 0; q < 4; q++) {
    const _Float16 hh = (_Float16)v[q];
    h4[q] = hh;
    q4[q] = (_Float16)((v[q] - (float)hh) * 2048.0f);
  }
  const int s = r >> 5, l31 = r & 31;
  const int lh = c >> 1, j4 = (c & 1) * 4;
  const int lane = l31 + (lh << 5);
  _Float16* base = A3 + (size_t)kb * AKBF;
  *(f16x4*)(base + ((s * 2 + 0) * 64 + lane) * 8 + j4) = h4;
  *(f16x4*)(base + ((s * 2 + 1) * 64 + lane) * 8 + j4) = q4;
}

// ---------------- MFMA f16-split GEMM: A in regs, B in LDS, K-step 32 ----------------
// 32 barrier-iterations (was 64): each stages a 64x32 B tile (two 16-k sub-tiles) and
// runs 24 MFMAs. A: 8x16B coalesced register loads/iter from fragment-ordered A3.
__global__ __launch_bounds__(256, 2) void gemm_f16s(
    const float* __restrict__ Bm, const _Float16* __restrict__ A3,
    const float* __restrict__ temp, unsigned* __restrict__ rowmax,
    float* __restrict__ C) {
  __shared__ _Float16 Bls[2][2][GN * BSTR];  // dbuf x sub-k x 5120 f16 = 20,480 B
  __shared__ float s_invT[256];
  __shared__ unsigned s_pm[256];

  const int t = threadIdx.x;
  const int l = t & 63, w = t >> 6;
  const int n0 = blockIdx.x * GN;
  s_invT[t] = 1.0f / temp[t];
  s_pm[t] = 0u;

  f32x16 accH[2][2] = {};  // [strip][ncol] h*h'
  f32x16 accC[2][2] = {};  // h*q' + q*h' (scaled by 2048)

  const int bn = t >> 2, k8 = (t & 3) * 8;   // 4 threads/row, 8 consecutive k each
  const int sub = k8 >> 4, kk = k8 & 15;     // sub-tile and offset within it
  const int l31 = l & 31, lh = l >> 5;
  const int ka = lh * 8;
  const int mb = w * 64;

  const float* browp = Bm + (size_t)(n0 + bn) * ND + k8;
  const _Float16* aB = A3 + 2048 * w + l * 8;

  // A fragments for even/odd iterations, 2 sub-k-blocks each
  f16x8 eh0_0, eq0_0, eh1_0, eq1_0, eh0_1, eq0_1, eh1_1, eq1_1;
  f16x8 oh0_0, oq0_0, oh1_0, oq1_0, oh0_1, oq0_1, oh1_1, oq1_1;

#define LOADA32(P, KB2)                                               \
  do {                                                                \
    const _Float16* a0_ = aB + (size_t)(2 * (KB2)) * AKBF;            \
    P##h0_0 = *(const f16x8*)(a0_);                                   \
    P##q0_0 = *(const f16x8*)(a0_ + 512);                             \
    P##h1_0 = *(const f16x8*)(a0_ + 1024);                            \
    P##q1_0 = *(const f16x8*)(a0_ + 1536);                            \
    const _Float16* a1_ = a0_ + AKBF;                                 \
    P##h0_1 = *(const f16x8*)(a1_);                                   \
    P##q0_1 = *(const f16x8*)(a1_ + 512);                             \
    P##h1_1 = *(const f16x8*)(a1_ + 1024);                            \
    P##q1_1 = *(const f16x8*)(a1_ + 1536);                            \
  } while (0)

#define BCONV32(V0, V1, BUF)                                          \
  do {                                                                \
    const float vv_[8] = {(V0).x, (V0).y, (V0).z, (V0).w,             \
                          (V1).x, (V1).y, (V1).z, (V1).w};            \
    f16x8 h8_, q8_;                                                   \
    _Pragma("unroll") for (int j_ = 0; j_ < 8; j_++) {                \
      const _Float16 h_ = (_Float16)vv_[j_];                          \
      h8_[j_] = h_;                                                   \
      q8_[j_] = (_Float16)((vv_[j_] - (float)h_) * 2048.0f);          \
    }                                                                 \
    _Float16* prow_ = &Bls[BUF][sub][0] + bn * BSTR;                  \
    *(f16x8*)(prow_ + kk) = h8_;                                      \
    *(f16x8*)(prow_ + 16 + kk) = q8_;                                 \
  } while (0)

#define CSUB(H0, Q0, H1, Q1, CUR, S)                                                     \
  do {                                                                                   \
    const _Float16* Bp_ = &Bls[CUR][S][0] + (size_t)l31 * BSTR + ka;                     \
    f16x8 b0h_ = *(const f16x8*)(Bp_);                                                   \
    f16x8 b1h_ = *(const f16x8*)(Bp_ + 32 * BSTR);                                       \
    accH[0][0] = __builtin_amdgcn_mfma_f32_32x32x16_f16(H0, b0h_, accH[0][0], 0, 0, 0);  \
    accH[0][1] = __builtin_amdgcn_mfma_f32_32x32x16_f16(H0, b1h_, accH[0][1], 0, 0, 0);  \
    accH[1][0] = __builtin_amdgcn_mfma_f32_32x32x16_f16(H1, b0h_, accH[1][0], 0, 0, 0);  \
    accH[1][1] = __builtin_amdgcn_mfma_f32_32x32x16_f16(H1, b1h_, accH[1][1], 0, 0, 0);  \
    f16x8 b0q_ = *(const f16x8*)(Bp_ + 16);                                              \
    f16x8 b1q_ = *(const f16x8*)(Bp_ + 32 * BSTR + 16);                                  \
    accC[0][0] = __builtin_amdgcn_mfma_f32_32x32x16_f16(H0, b0q_, accC[0][0], 0, 0, 0);  \
    accC[0][1] = __builtin_amdgcn_mfma_f32_32x32x16_f16(H0, b1q_, accC[0][1], 0, 0, 0);  \
    accC[1][0] = __builtin_amdgcn_mfma_f32_32x32x16_f16(H1, b0q_, accC[1][0], 0, 0, 0);  \
    accC[1][1] = __builtin_amdgcn_mfma_f32_32x32x16_f16(H1, b1q_, accC[1][1], 0, 0, 0);  \
    accC[0][0] = __builtin_amdgcn_mfma_f32_32x32x16_f16(Q0, b0h_, accC[0][0], 0, 0, 0);  \
    accC[0][1] = __builtin_amdgcn_mfma_f32_32x32x16_f16(Q0, b1h_, accC[0][1], 0, 0, 0);  \
    accC[1][0] = __builtin_amdgcn_mfma_f32_32x32x16_f16(Q1, b0h_, accC[1][0], 0, 0, 0);  \
    accC[1][1] = __builtin_amdgcn_mfma_f32_32x32x16_f16(Q1, b1h_, accC[1][1], 0, 0, 0);  \
  } while (0)

#define COMPUTE32(P, CUR)                                             \
  do {                                                                \
    CSUB(P##h0_0, P##q0_0, P##h1_0, P##q1_0, CUR, 0);                 \
    CSUB(P##h0_1, P##q0_1, P##h1_1, P##q1_1, CUR, 1);                 \
  } while (0)

  // ---- prologue: A(0)->e, A(1)->o, B(0) built, f4(1) in flight ----
  LOADA32(e, 0);
  __builtin_amdgcn_sched_barrier(0);
  float4 b00 = *(const float4*)(browp);
  float4 b01 = *(const float4*)(browp + 4);
  __builtin_amdgcn_sched_barrier(0);
  LOADA32(o, 1);
  __builtin_amdgcn_sched_barrier(0);
  float4 bvA0 = *(const float4*)(browp + 32);
  float4 bvA1 = *(const float4*)(browp + 36);
  __builtin_amdgcn_sched_barrier(0);
  BCONV32(b00, b01, 0);
  asm volatile("s_waitcnt lgkmcnt(0)\ns_barrier" ::: "memory");

  float4 bvB0, bvB1;
  // invariant entering pair kb2: e=A(kb2), o=A(kb2+1), Bls[0]=B(kb2), bvA=f4(kb2+1)
  for (int kb2 = 0; kb2 < 30; kb2 += 2) {
    COMPUTE32(e, 0);
    __builtin_amdgcn_sched_barrier(0);
    LOADA32(e, kb2 + 2);
    __builtin_amdgcn_sched_barrier(0);
    bvB0 = *(const float4*)(browp + (size_t)(kb2 + 2) * 32);
    bvB1 = *(const float4*)(browp + (size_t)(kb2 + 2) * 32 + 4);
    __builtin_amdgcn_sched_barrier(0);
    BCONV32(bvA0, bvA1, 1);
    asm volatile("s_waitcnt lgkmcnt(0)\ns_barrier" ::: "memory");

    COMPUTE32(o, 1);
    __builtin_amdgcn_sched_barrier(0);
    LOADA32(o, kb2 + 3);
    __builtin_amdgcn_sched_barrier(0);
    bvA0 = *(const float4*)(browp + (size_t)(kb2 + 3) * 32);
    bvA1 = *(const float4*)(browp + (size_t)(kb2 + 3) * 32 + 4);
    __builtin_amdgcn_sched_barrier(0);
    BCONV32(bvB0, bvB1, 0);
    asm volatile("s_waitcnt lgkmcnt(0)\ns_barrier" ::: "memory");
  }
  // tail: e=A(30), o=A(31), Bls[0]=B(30), bvA=f4(31)
  COMPUTE32(e, 0);
  __builtin_amdgcn_sched_barrier(0);
  BCONV32(bvA0, bvA1, 1);
  asm volatile("s_waitcnt lgkmcnt(0)\ns_barrier" ::: "memory");
  COMPUTE32(o, 1);

#undef LOADA32
#undef BCONV32
#undef CSUB
#undef COMPUTE32

#pragma unroll
  for (int mi = 0; mi < 2; mi++) {
#pragma unroll
    for (int r = 0; r < 16; r++) {
      const int row = mb + mi * 32 + (r & 3) + 8 * (r >> 2) + 4 * lh;
      const float it = s_invT[row];
      float v0 = (accH[mi][0][r] + accC[mi][0][r] * INV2048F) * it;
      float v1 = (accH[mi][1][r] + accC[mi][1][r] * INV2048F) * it;
      C[(size_t)row * NV + n0 + l31] = v0;
      C[(size_t)row * NV + n0 + 32 + l31] = v1;
      float mx = fmaxf(v0, v1);
#pragma unroll
      for (int o = 1; o < 32; o <<= 1) mx = fmaxf(mx, __shfl_xor(mx, o));
      if (l31 == 0) atomicMax(&s_pm[row], mono_enc(mx));
    }
  }
  __syncthreads();
  atomicMax(&rowmax[t], s_pm[t]);
}

// ---------------- fused per-row sampler: shfl-scan + integer fixed-point HACC --------
__global__ __launch_bounds__(1024) void sample_row(
    float* __restrict__ buf, const unsigned* __restrict__ rowmax,
    const int* __restrict__ toks, const float* __restrict__ pres,
    const float* __restrict__ freq, const float* __restrict__ temp,
    const float* __restrict__ topp_a, const int* __restrict__ topk_a) {
  extern __shared__ char smem[];
  float* e = (float*)smem;
  unsigned* hist = (unsigned*)(smem + NV * 4);
  unsigned long long* suf = (unsigned long long*)hist;  // aliases lo0|lo1
  __shared__ unsigned long long wtot16[16];
  __shared__ int s_tok[NT];
  __shared__ int s_bs;
  __shared__ RowP2 sp;

  const int b = blockIdx.x, t = threadIdx.x;
  const int cp = (t >> 6) & 1;
  unsigned* loP = hist + cp * HSTR;
  unsigned* hcP = hist + 2 * HSTR + cp * HSTR;
  float* row = buf + (size_t)b * NV;

// exact u48 fixed-point of e (float bits K, K!=0): trunc(e * 2^32), integer-only.
// m<<(exp-118) reproduces (u64)((double)e*2^32) bit-for-bit for normals; denorm->0.
#define HACC(K, BIN)                                                            \
  do {                                                                          \
    unsigned long long m_ = (unsigned long long)(((K) & 0x7FFFFFu) | 0x800000u);\
    const int sh_ = (int)((K) >> 23) - 118;                                     \
    const unsigned long long f_ =                                               \
        (sh_ >= 0) ? (m_ << sh_) : ((sh_ > -24) ? (m_ >> (-sh_)) : 0ull);       \
    const unsigned flo_ = (unsigned)f_;                                         \
    const unsigned old_ = atomicAdd(&loP[BIN], flo_);                           \
    const unsigned hc_ = 0x10000u + (unsigned)(f_ >> 32) +                      \
                         ((old_ + flo_ < flo_) ? 1u : 0u);                      \
    atomicAdd(&hcP[BIN], hc_);                                                  \
  } while (0)

  if (t < NT) s_tok[t] = toks[b * NT + t];
  for (int i = t; i < HTOT; i += 1024) hist[i] = 0u;
  for (int i4 = t; i4 < NV / 4; i4 += 1024)
    *(float4*)(e + i4 * 4) = *(const float4*)(row + i4 * 4);
  __syncthreads();

  if (t < NT) {
    const int tk = s_tok[t];
    bool first = true; int cnt = 0;
    for (int j = 0; j < NT; j++)
      if (s_tok[j] == tk) { if (j < t) first = false; cnt++; }
    if (first) e[tk] -= (freq[b] * (float)cnt + pres[b]) / temp[b];
  }
  __syncthreads();

  const float M = mono_dec(rowmax[b]);
  for (int i4 = t; i4 < NV / 4; i4 += 1024) {
    float4 x4 = *(const float4*)(e + i4 * 4);
    float4 e4;
    e4.x = expf(x4.x - M); e4.y = expf(x4.y - M);
    e4.z = expf(x4.z - M); e4.w = expf(x4.w - M);
    *(float4*)(e + i4 * 4) = e4;
    unsigned k;
    k = __float_as_uint(e4.x); if (k) HACC(k, k >> 20);
    k = __float_as_uint(e4.y); if (k) HACC(k, k >> 20);
    k = __float_as_uint(e4.z); if (k) HACC(k, k >> 20);
    k = __float_as_uint(e4.w); if (k) HACC(k, k >> 20);
  }
  __syncthreads();

  const int lane = t & 63, wv = t >> 6;
  for (int level = 0; level < 3; level++) {
    // per-bin packed (count<<48 | sum) from the 2 privatized copies
    const unsigned lo0 = hist[t], lo1 = hist[HSTR + t];
    const unsigned hc0 = hist[2 * HSTR + t], hc1 = hist[3 * HSTR + t];
    const unsigned c = (hc0 >> 16) + (hc1 >> 16);
    const unsigned long long sum =
        (((unsigned long long)((hc0 & 0xFFFFu) + (hc1 & 0xFFFFu))) << 32) +
        (unsigned long long)lo0 + (unsigned long long)lo1;
    unsigned long long sv = ((unsigned long long)c << 48) + sum;
    // in-wave suffix scan over bins (integer adds: exact, order-free)
#pragma unroll
    for (int off = 1; off < 64; off <<= 1) {
      const unsigned long long up = __shfl_down(sv, off, 64);
      if (lane + off < 64) sv += up;
    }
    if (lane == 0) wtot16[wv] = sv;
    if (t == 0) s_bs = NBIN - 1;
    __syncthreads();  // hist reads done; wtot16 visible
    unsigned long long add = 0ull, tot = 0ull;
#pragma unroll
    for (int w2 = 0; w2 < 16; w2++) {
      const unsigned long long x = wtot16[w2];
      tot += x;
      add += (w2 > wv) ? x : 0ull;
    }
    const unsigned long long mySuf = sv + add;
    suf[t] = mySuf;
    const unsigned long long totalP = tot;
    __syncthreads();  // suf ready

    unsigned long long base, toppZ;
    int ktop_;
    if (level == 0) {
      ktop_ = topk_a[b];
      unsigned long long Zfix = totalP & SMASK;
      if (!Zfix) Zfix = 1ull;
      toppZ = (unsigned long long)((double)topp_a[b] * (double)Zfix);
      base = 0ull;
    } else {
      base = sp.basePack; toppZ = sp.toppZfix; ktop_ = sp.ktop;
    }

    {
      const unsigned long long sG = base + mySuf;
      const bool A = ((long long)(sG >> 48) < (long long)ktop_) && ((sG & SMASK) <= toppZ);
      const unsigned long long sP = base + ((t > 0) ? suf[t - 1] : totalP);
      const bool Ap = ((long long)(sP >> 48) < (long long)ktop_) && ((sP & SMASK) <= toppZ);
      if (A && !Ap) s_bs = t;
    }
    __syncthreads();
    if (t == 0) {
      const int bs = s_bs;
      const unsigned long long newBase = base + suf[bs];
      if (level == 0) {
        unsigned long long Zfix = totalP & SMASK;
        if (!Zfix) Zfix = 1ull;
        sp.invZ = (float)(FIX2 / (double)Zfix);
      }
      if (level < 2) {
        sp.basePack = newBase;
        sp.toppZfix = toppZ;
        sp.ktop = ktop_;
        sp.pfx = (level == 0) ? (unsigned)bs : ((sp.pfx << 10) | (unsigned)bs);
      } else {
        const unsigned ustar = (sp.pfx << 10) | (unsigned)bs;
        const unsigned long long raw = ((bs > 0) ? suf[bs - 1] : totalP) - suf[bs];
        const int cEq = (int)(raw >> 48);
        const long long Chi = (long long)(newBase >> 48);
        const unsigned long long Shi = newBase & SMASK;
        long long m = cEq;
        const long long lim = (long long)ktop_ - Chi;
        if (lim < m) m = lim;
        const double tf = (double)__uint_as_float(ustar) * FIX2;
        const double rem = (double)(toppZ - Shi);
        const double Rd = floor(rem / tf) + 1.0;
        if (Rd < (double)m) m = (long long)Rd;
        if (m < 1) m = 1;
        sp.ustar = ustar; sp.m = (int)m; sp.cEq = cEq;
      }
    }
    __syncthreads();

    if (level < 2) {
      for (int i = t; i < HTOT; i += 1024) hist[i] = 0u;
      __syncthreads();
      const unsigned pfx = sp.pfx;
      const int ms = (level == 0) ? 20 : 10;
      const int bsh = (level == 0) ? 10 : 0;
      for (int i4 = t; i4 < NV / 4; i4 += 1024) {
        float4 e4 = *(const float4*)(e + i4 * 4);
        unsigned k;
        k = __float_as_uint(e4.x); if (k && (k >> ms) == pfx) HACC(k, (k >> bsh) & 1023u);
        k = __float_as_uint(e4.y); if (k && (k >> ms) == pfx) HACC(k, (k >> bsh) & 1023u);
        k = __float_as_uint(e4.z); if (k && (k >> ms) == pfx) HACC(k, (k >> bsh) & 1023u);
        k = __float_as_uint(e4.w); if (k && (k >> ms) == pfx) HACC(k, (k >> bsh) & 1023u);
      }
      __syncthreads();
    }
  }
#undef HACC

  const unsigned ustar = sp.ustar;
  const float invZ = sp.invZ;
  if (sp.m >= sp.cEq) {
    for (int i4 = t; i4 < NV / 4; i4 += 1024) {
      float4 e4 = *(const float4*)(e + i4 * 4);
      float4 o4;
      unsigned k;
      k = __float_as_uint(e4.x); o4.x = (k >= ustar) ? e4.x * invZ : 0.f;
      k = __float_as_uint(e4.y); o4.y = (k >= ustar) ? e4.y * invZ : 0.f;
      k = __float_as_uint(e4.z); o4.z = (k >= ustar) ? e4.z * invZ : 0.f;
      k = __float_as_uint(e4.w); o4.w = (k >= ustar) ? e4.w * invZ : 0.f;
      *(float4*)(row + i4 * 4) = o4;
    }
  } else {
    const int m = sp.m;
    unsigned* rk = hist;
    const int base0 = t * 32;
    const int end0 = (base0 + 32 < NV) ? base0 + 32 : NV;
    int myc = 0;
    for (int v = base0; v < end0; v++)
      myc += (__float_as_uint(e[v]) == ustar);
    rk[t] = (unsigned)myc;
    __syncthreads();
    for (int off = 1; off < 1024; off <<= 1) {
      const unsigned a0 = rk[t];
      const unsigned an = (t >= off) ? rk[t - off] : 0u;
      __syncthreads();
      rk[t] = a0 + an;
      __syncthreads();
    }
    int r = (t > 0) ? (int)rk[t - 1] : 0;
    for (int v = base0; v < end0; v++) {
      const unsigned k = __float_as_uint(e[v]);
      float o = (k > ustar) ? e[v] * invZ : 0.f;
      if (k == ustar) { o = (r < m) ? e[v] * invZ : 0.f; r++; }
      row[v] = o;
    }
  }
}

extern "C" void kernel_launch(void* const* d_in, const int* in_sizes, int n_in,
                              void* d_out, int out_size, void* d_ws, size_t ws_size,
                              hipStream_t stream) {
  (void)in_sizes; (void)n_in; (void)out_size; (void)ws_size;
  const float* hidden = (const float*)d_in[0];
  const float* emb    = (const float*)d_in[1];
  const int*   toks   = (const int*)d_in[2];
  const float* pres   = (const float*)d_in[3];
  const float* freq   = (const float*)d_in[4];
  const float* temp   = (const float*)d_in[5];
  const float* topp   = (const float*)d_in[6];
  const int*   topk   = (const int*)d_in[7];
  float* out = (float*)d_out;

  // ws layout: A3 (64*16384 = 1,048,576 B) + rowmax (1,024 B, zeroed)
  const size_t offA3 = 0;
  const size_t offRM = 1048576;

  _Float16* A3 = (_Float16*)((char*)d_ws + offA3);
  unsigned* rowmax = (unsigned*)((char*)d_ws + offRM);

  hipFuncSetAttribute((const void*)sample_row,
                      hipFuncAttributeMaxDynamicSharedMemorySize, SMEM_BYTES);

  hipMemsetAsync((char*)d_ws + offRM, 0, 1024, stream);
  convert_A<<<256, 256, 0, stream>>>(hidden, A3);
  gemm_f16s<<<NGBLK, 256, 0, stream>>>(emb, A3, temp, rowmax, out);
  sample_row<<<NB, 1024, SMEM_BYTES, stream>>>(out, rowmax, toks, pres, freq,
                                               temp, topp, topk);
}

// Round 9
// 275.270 us; speedup vs baseline: 1.2663x; 1.2663x over previous
//
#include <hip/hip_runtime.h>
#include <math.h>

#define NB 256
#define NV 32000
#define ND 1024
#define NT 64

// ---- GEMM config ----
#define GN 64
#define BSTR 40            // B row stride (f16): [h x16][q x16][pad x8]
#define NKB 64             // 1024/16 k-blocks
#define AKBF 8192          // f16 per k-block, fragment order: 8 strips x 2(h,q) x 64 lanes x 8
#define NGBLK (NV / GN)    // 500
#define INV2048F 4.8828125e-4f

// ---- sampling config ----
#define NBIN 1024
#define HSTR 1032
#define HTOT (4 * HSTR)
#define FIX2 4294967296.0
#define SMASK ((1ull << 48) - 1ull)
#define SMEM_BYTES (NV * 4 + HTOT * 4)  // 144512 B

typedef _Float16 f16x8 __attribute__((ext_vector_type(8)));
typedef _Float16 f16x4 __attribute__((ext_vector_type(4)));
typedef float f32x16 __attribute__((ext_vector_type(16)));

struct RowP2 {
  unsigned long long basePack;
  unsigned long long toppZfix;
  unsigned pfx;
  int ktop;
  float invZ;
  unsigned ustar;
  int m;
  int cEq;
};

__device__ __forceinline__ unsigned mono_enc(float f) {
  unsigned u = __float_as_uint(f);
  return (u & 0x80000000u) ? ~u : (u | 0x80000000u);
}
__device__ __forceinline__ float mono_dec(unsigned u) {
  return (u & 0x80000000u) ? __uint_as_float(u & 0x7FFFFFFFu) : __uint_as_float(~u);
}

// ---------------- convert A: write MFMA-fragment-ordered h/q planes (R7) ------------
__global__ __launch_bounds__(256) void convert_A(const float* __restrict__ hidden,
                                                 _Float16* __restrict__ A3) {
  const int g = blockIdx.x * 256 + threadIdx.x;   // 65536 total
  const int kb = g >> 10, rem = g & 1023, r = rem >> 2, c = rem & 3;
  const float4 a4 = *(const float4*)(hidden + (size_t)r * ND + kb * 16 + c * 4);
  const float v[4] = {a4.x, a4.y, a4.z, a4.w};
  f16x4 h4, q4;
#pragma unroll
  for (int q = 0; q < 4; q++) {
    const _Float16 hh = (_Float16)v[q];
    h4[q] = hh;
    q4[q] = (_Float16)((v[q] - (float)hh) * 2048.0f);
  }
  const int s = r >> 5, l31 = r & 31;
  const int lh = c >> 1, j4 = (c & 1) * 4;
  const int lane = l31 + (lh << 5);
  _Float16* base = A3 + (size_t)kb * AKBF;
  *(f16x4*)(base + ((s * 2 + 0) * 64 + lane) * 8 + j4) = h4;
  *(f16x4*)(base + ((s * 2 + 1) * 64 + lane) * 8 + j4) = q4;
}

// ---------------- MFMA f16-split GEMM: A in registers, B in LDS dbuf (exact R7) -----
// R8 lesson: K-step 32 spilled (VGPR cap 128 @ 2 waves/SIMD vs ~200 live). K-step 16
// with 2-deep A register prefetch is the no-spill sweet spot: 108 VGPR, 81 us.
__global__ __launch_bounds__(256, 2) void gemm_f16s(
    const float* __restrict__ Bm, const _Float16* __restrict__ A3,
    const float* __restrict__ temp, unsigned* __restrict__ rowmax,
    float* __restrict__ C) {
  __shared__ _Float16 Bls[2][GN * BSTR];  // 10,240 B
  __shared__ float s_invT[256];
  __shared__ unsigned s_pm[256];

  const int t = threadIdx.x;
  const int l = t & 63, w = t >> 6;
  const int n0 = blockIdx.x * GN;
  s_invT[t] = 1.0f / temp[t];
  s_pm[t] = 0u;

  f32x16 accH[2][2] = {};  // [strip][ncol] h*h'
  f32x16 accC[2][2] = {};  // h*q' + q*h' (scaled by 2048)

  const int bn = t >> 2, bk4 = (t & 3) * 4;
  const int l31 = l & 31, lh = l >> 5;
  const int ka = lh * 8;
  const int mb = w * 64;

  const float* browp = Bm + (size_t)(n0 + bn) * ND + bk4;
  const _Float16* aB = A3 + 2048 * w + l * 8;

  f16x8 eh0, eh1, eq0, eq1;  // even-iteration A fragments
  f16x8 oh0, oh1, oq0, oq1;  // odd-iteration A fragments

#define LOADA(P, KB)                                                  \
  do {                                                                \
    const _Float16* ap_ = aB + (size_t)(KB) * AKBF;                   \
    P##h0 = *(const f16x8*)(ap_);                                     \
    P##q0 = *(const f16x8*)(ap_ + 512);                               \
    P##h1 = *(const f16x8*)(ap_ + 1024);                              \
    P##q1 = *(const f16x8*)(ap_ + 1536);                              \
  } while (0)

#define BCONV(BV, DST)                                                \
  do {                                                                \
    f16x4 h4_, q4_;                                                   \
    const float vv_[4] = {(BV).x, (BV).y, (BV).z, (BV).w};            \
    _Pragma("unroll") for (int j_ = 0; j_ < 4; j_++) {                \
      const _Float16 h_ = (_Float16)vv_[j_];                          \
      h4_[j_] = h_;                                                   \
      q4_[j_] = (_Float16)((vv_[j_] - (float)h_) * 2048.0f);          \
    }                                                                 \
    _Float16* prow_ = (DST) + bn * BSTR;                              \
    *(f16x4*)(prow_ + bk4) = h4_;                                     \
    *(f16x4*)(prow_ + 16 + bk4) = q4_;                                \
  } while (0)

#define COMPUTE(P, CUR)                                                                     \
  do {                                                                                      \
    const _Float16* Bp_ = &Bls[CUR][0] + (size_t)l31 * BSTR + ka;                           \
    f16x8 b0h_ = *(const f16x8*)(Bp_);                                                      \
    f16x8 b1h_ = *(const f16x8*)(Bp_ + 32 * BSTR);                                          \
    accH[0][0] = __builtin_amdgcn_mfma_f32_32x32x16_f16(P##h0, b0h_, accH[0][0], 0, 0, 0);  \
    accH[0][1] = __builtin_amdgcn_mfma_f32_32x32x16_f16(P##h0, b1h_, accH[0][1], 0, 0, 0);  \
    accH[1][0] = __builtin_amdgcn_mfma_f32_32x32x16_f16(P##h1, b0h_, accH[1][0], 0, 0, 0);  \
    accH[1][1] = __builtin_amdgcn_mfma_f32_32x32x16_f16(P##h1, b1h_, accH[1][1], 0, 0, 0);  \
    f16x8 b0q_ = *(const f16x8*)(Bp_ + 16);                                                 \
    f16x8 b1q_ = *(const f16x8*)(Bp_ + 32 * BSTR + 16);                                     \
    accC[0][0] = __builtin_amdgcn_mfma_f32_32x32x16_f16(P##h0, b0q_, accC[0][0], 0, 0, 0);  \
    accC[0][1] = __builtin_amdgcn_mfma_f32_32x32x16_f16(P##h0, b1q_, accC[0][1], 0, 0, 0);  \
    accC[1][0] = __builtin_amdgcn_mfma_f32_32x32x16_f16(P##h1, b0q_, accC[1][0], 0, 0, 0);  \
    accC[1][1] = __builtin_amdgcn_mfma_f32_32x32x16_f16(P##h1, b1q_, accC[1][1], 0, 0, 0);  \
    accC[0][0] = __builtin_amdgcn_mfma_f32_32x32x16_f16(P##q0, b0h_, accC[0][0], 0, 0, 0);  \
    accC[0][1] = __builtin_amdgcn_mfma_f32_32x32x16_f16(P##q0, b1h_, accC[0][1], 0, 0, 0);  \
    accC[1][0] = __builtin_amdgcn_mfma_f32_32x32x16_f16(P##q1, b0h_, accC[1][0], 0, 0, 0);  \
    accC[1][1] = __builtin_amdgcn_mfma_f32_32x32x16_f16(P##q1, b1h_, accC[1][1], 0, 0, 0);  \
  } while (0)

  // ---- prologue: A(0)->e, A(1)->o, B(0) built, f4(1) in flight ----
  LOADA(e, 0);
  __builtin_amdgcn_sched_barrier(0);
  float4 bv0 = *(const float4*)(browp);
  __builtin_amdgcn_sched_barrier(0);
  LOADA(o, 1);
  __builtin_amdgcn_sched_barrier(0);
  float4 bvA = *(const float4*)(browp + 16);  // f4(1)
  __builtin_amdgcn_sched_barrier(0);
  BCONV(bv0, &Bls[0][0]);
  asm volatile("s_waitcnt lgkmcnt(0)\ns_barrier" ::: "memory");

  float4 bvB;
  // invariant entering pair kb: e=A(kb), o=A(kb+1), Bls[0]=B(kb), bvA=f4(kb+1)
  for (int kb = 0; kb < 62; kb += 2) {
    COMPUTE(e, 0);
    __builtin_amdgcn_sched_barrier(0);
    LOADA(e, kb + 2);
    __builtin_amdgcn_sched_barrier(0);
    bvB = *(const float4*)(browp + (size_t)(kb + 2) * 16);
    __builtin_amdgcn_sched_barrier(0);
    BCONV(bvA, &Bls[1][0]);
    asm volatile("s_waitcnt lgkmcnt(0)\ns_barrier" ::: "memory");

    COMPUTE(o, 1);
    __builtin_amdgcn_sched_barrier(0);
    LOADA(o, kb + 3);
    __builtin_amdgcn_sched_barrier(0);
    bvA = *(const float4*)(browp + (size_t)(kb + 3) * 16);
    __builtin_amdgcn_sched_barrier(0);
    BCONV(bvB, &Bls[0][0]);
    asm volatile("s_waitcnt lgkmcnt(0)\ns_barrier" ::: "memory");
  }
  // tail: e=A(62), o=A(63), Bls[0]=B(62), bvA=f4(63)
  COMPUTE(e, 0);
  __builtin_amdgcn_sched_barrier(0);
  BCONV(bvA, &Bls[1][0]);
  asm volatile("s_waitcnt lgkmcnt(0)\ns_barrier" ::: "memory");
  COMPUTE(o, 1);

#undef LOADA
#undef BCONV
#undef COMPUTE

#pragma unroll
  for (int mi = 0; mi < 2; mi++) {
#pragma unroll
    for (int r = 0; r < 16; r++) {
      const int row = mb + mi * 32 + (r & 3) + 8 * (r >> 2) + 4 * lh;
      const float it = s_invT[row];
      float v0 = (accH[mi][0][r] + accC[mi][0][r] * INV2048F) * it;
      float v1 = (accH[mi][1][r] + accC[mi][1][r] * INV2048F) * it;
      C[(size_t)row * NV + n0 + l31] = v0;
      C[(size_t)row * NV + n0 + 32 + l31] = v1;
      float mx = fmaxf(v0, v1);
#pragma unroll
      for (int o = 1; o < 32; o <<= 1) mx = fmaxf(mx, __shfl_xor(mx, o));
      if (l31 == 0) atomicMax(&s_pm[row], mono_enc(mx));
    }
  }
  __syncthreads();
  atomicMax(&rowmax[t], s_pm[t]);
}

// ---------------- fused per-row sampler: shfl-scan + integer fixed-point HACC (R8) --
__global__ __launch_bounds__(1024) void sample_row(
    float* __restrict__ buf, const unsigned* __restrict__ rowmax,
    const int* __restrict__ toks, const float* __restrict__ pres,
    const float* __restrict__ freq, const float* __restrict__ temp,
    const float* __restrict__ topp_a, const int* __restrict__ topk_a) {
  extern __shared__ char smem[];
  float* e = (float*)smem;
  unsigned* hist = (unsigned*)(smem + NV * 4);
  unsigned long long* suf = (unsigned long long*)hist;  // aliases lo0|lo1
  __shared__ unsigned long long wtot16[16];
  __shared__ int s_tok[NT];
  __shared__ int s_bs;
  __shared__ RowP2 sp;

  const int b = blockIdx.x, t = threadIdx.x;
  const int cp = (t >> 6) & 1;
  unsigned* loP = hist + cp * HSTR;
  unsigned* hcP = hist + 2 * HSTR + cp * HSTR;
  float* row = buf + (size_t)b * NV;

// exact u48 fixed-point of e (float bits K, K!=0): trunc(e * 2^32), integer-only.
#define HACC(K, BIN)                                                            \
  do {                                                                          \
    unsigned long long m_ = (unsigned long long)(((K) & 0x7FFFFFu) | 0x800000u);\
    const int sh_ = (int)((K) >> 23) - 118;                                     \
    const unsigned long long f_ =                                               \
        (sh_ >= 0) ? (m_ << sh_) : ((sh_ > -24) ? (m_ >> (-sh_)) : 0ull);       \
    const unsigned flo_ = (unsigned)f_;                                         \
    const unsigned old_ = atomicAdd(&loP[BIN], flo_);                           \
    const unsigned hc_ = 0x10000u + (unsigned)(f_ >> 32) +                      \
                         ((old_ + flo_ < flo_) ? 1u : 0u);                      \
    atomicAdd(&hcP[BIN], hc_);                                                  \
  } while (0)

  if (t < NT) s_tok[t] = toks[b * NT + t];
  for (int i = t; i < HTOT; i += 1024) hist[i] = 0u;
  for (int i4 = t; i4 < NV / 4; i4 += 1024)
    *(float4*)(e + i4 * 4) = *(const float4*)(row + i4 * 4);
  __syncthreads();

  if (t < NT) {
    const int tk = s_tok[t];
    bool first = true; int cnt = 0;
    for (int j = 0; j < NT; j++)
      if (s_tok[j] == tk) { if (j < t) first = false; cnt++; }
    if (first) e[tk] -= (freq[b] * (float)cnt + pres[b]) / temp[b];
  }
  __syncthreads();

  const float M = mono_dec(rowmax[b]);
  for (int i4 = t; i4 < NV / 4; i4 += 1024) {
    float4 x4 = *(const float4*)(e + i4 * 4);
    float4 e4;
    e4.x = expf(x4.x - M); e4.y = expf(x4.y - M);
    e4.z = expf(x4.z - M); e4.w = expf(x4.w - M);
    *(float4*)(e + i4 * 4) = e4;
    unsigned k;
    k = __float_as_uint(e4.x); if (k) HACC(k, k >> 20);
    k = __float_as_uint(e4.y); if (k) HACC(k, k >> 20);
    k = __float_as_uint(e4.z); if (k) HACC(k, k >> 20);
    k = __float_as_uint(e4.w); if (k) HACC(k, k >> 20);
  }
  __syncthreads();

  const int lane = t & 63, wv = t >> 6;
  for (int level = 0; level < 3; level++) {
    // per-bin packed (count<<48 | sum) from the 2 privatized copies
    const unsigned lo0 = hist[t], lo1 = hist[HSTR + t];
    const unsigned hc0 = hist[2 * HSTR + t], hc1 = hist[3 * HSTR + t];
    const unsigned c = (hc0 >> 16) + (hc1 >> 16);
    const unsigned long long sum =
        (((unsigned long long)((hc0 & 0xFFFFu) + (hc1 & 0xFFFFu))) << 32) +
        (unsigned long long)lo0 + (unsigned long long)lo1;
    unsigned long long sv = ((unsigned long long)c << 48) + sum;
    // in-wave suffix scan over bins (integer adds: exact, order-free)
#pragma unroll
    for (int off = 1; off < 64; off <<= 1) {
      const unsigned long long up = __shfl_down(sv, off, 64);
      if (lane + off < 64) sv += up;
    }
    if (lane == 0) wtot16[wv] = sv;
    if (t == 0) s_bs = NBIN - 1;
    __syncthreads();  // hist reads done; wtot16 visible
    unsigned long long add = 0ull, tot = 0ull;
#pragma unroll
    for (int w2 = 0; w2 < 16; w2++) {
      const unsigned long long x = wtot16[w2];
      tot += x;
      add += (w2 > wv) ? x : 0ull;
    }
    const unsigned long long mySuf = sv + add;
    suf[t] = mySuf;
    const unsigned long long totalP = tot;
    __syncthreads();  // suf ready

    unsigned long long base, toppZ;
    int ktop_;
    if (level == 0) {
      ktop_ = topk_a[b];
      unsigned long long Zfix = totalP & SMASK;
      if (!Zfix) Zfix = 1ull;
      toppZ = (unsigned long long)((double)topp_a[b] * (double)Zfix);
      base = 0ull;
    } else {
      base = sp.basePack; toppZ = sp.toppZfix; ktop_ = sp.ktop;
    }

    {
      const unsigned long long sG = base + mySuf;
      const bool A = ((long long)(sG >> 48) < (long long)ktop_) && ((sG & SMASK) <= toppZ);
      const unsigned long long sP = base + ((t > 0) ? suf[t - 1] : totalP);
      const bool Ap = ((long long)(sP >> 48) < (long long)ktop_) && ((sP & SMASK) <= toppZ);
      if (A && !Ap) s_bs = t;
    }
    __syncthreads();
    if (t == 0) {
      const int bs = s_bs;
      const unsigned long long newBase = base + suf[bs];
      if (level == 0) {
        unsigned long long Zfix = totalP & SMASK;
        if (!Zfix) Zfix = 1ull;
        sp.invZ = (float)(FIX2 / (double)Zfix);
      }
      if (level < 2) {
        sp.basePack = newBase;
        sp.toppZfix = toppZ;
        sp.ktop = ktop_;
        sp.pfx = (level == 0) ? (unsigned)bs : ((sp.pfx << 10) | (unsigned)bs);
      } else {
        const unsigned ustar = (sp.pfx << 10) | (unsigned)bs;
        const unsigned long long raw = ((bs > 0) ? suf[bs - 1] : totalP) - suf[bs];
        const int cEq = (int)(raw >> 48);
        const long long Chi = (long long)(newBase >> 48);
        const unsigned long long Shi = newBase & SMASK;
        long long m = cEq;
        const long long lim = (long long)ktop_ - Chi;
        if (lim < m) m = lim;
        const double tf = (double)__uint_as_float(ustar) * FIX2;
        const double rem = (double)(toppZ - Shi);
        const double Rd = floor(rem / tf) + 1.0;
        if (Rd < (double)m) m = (long long)Rd;
        if (m < 1) m = 1;
        sp.ustar = ustar; sp.m = (int)m; sp.cEq = cEq;
      }
    }
    __syncthreads();

    if (level < 2) {
      for (int i = t; i < HTOT; i += 1024) hist[i] = 0u;
      __syncthreads();
      const unsigned pfx = sp.pfx;
      const int ms = (level == 0) ? 20 : 10;
      const int bsh = (level == 0) ? 10 : 0;
      for (int i4 = t; i4 < NV / 4; i4 += 1024) {
        float4 e4 = *(const float4*)(e + i4 * 4);
        unsigned k;
        k = __float_as_uint(e4.x); if (k && (k >> ms) == pfx) HACC(k, (k >> bsh) & 1023u);
        k = __float_as_uint(e4.y); if (k && (k >> ms) == pfx) HACC(k, (k >> bsh) & 1023u);
        k = __float_as_uint(e4.z); if (k && (k >> ms) == pfx) HACC(k, (k >> bsh) & 1023u);
        k = __float_as_uint(e4.w); if (k && (k >> ms) == pfx) HACC(k, (k >> bsh) & 1023u);
      }
      __syncthreads();
    }
  }
#undef HACC

  const unsigned ustar = sp.ustar;
  const float invZ = sp.invZ;
  if (sp.m >= sp.cEq) {
    for (int i4 = t; i4 < NV / 4; i4 += 1024) {
      float4 e4 = *(const float4*)(e + i4 * 4);
      float4 o4;
      unsigned k;
      k = __float_as_uint(e4.x); o4.x = (k >= ustar) ? e4.x * invZ : 0.f;
      k = __float_as_uint(e4.y); o4.y = (k >= ustar) ? e4.y * invZ : 0.f;
      k = __float_as_uint(e4.z); o4.z = (k >= ustar) ? e4.z * invZ : 0.f;
      k = __float_as_uint(e4.w); o4.w = (k >= ustar) ? e4.w * invZ : 0.f;
      *(float4*)(row + i4 * 4) = o4;
    }
  } else {
    const int m = sp.m;
    unsigned* rk = hist;
    const int base0 = t * 32;
    const int end0 = (base0 + 32 < NV) ? base0 + 32 : NV;
    int myc = 0;
    for (int v = base0; v < end0; v++)
      myc += (__float_as_uint(e[v]) == ustar);
    rk[t] = (unsigned)myc;
    __syncthreads();
    for (int off = 1; off < 1024; off <<= 1) {
      const unsigned a0 = rk[t];
      const unsigned an = (t >= off) ? rk[t - off] : 0u;
      __syncthreads();
      rk[t] = a0 + an;
      __syncthreads();
    }
    int r = (t > 0) ? (int)rk[t - 1] : 0;
    for (int v = base0; v < end0; v++) {
      const unsigned k = __float_as_uint(e[v]);
      float o = (k > ustar) ? e[v] * invZ : 0.f;
      if (k == ustar) { o = (r < m) ? e[v] * invZ : 0.f; r++; }
      row[v] = o;
    }
  }
}

extern "C" void kernel_launch(void* const* d_in, const int* in_sizes, int n_in,
                              void* d_out, int out_size, void* d_ws, size_t ws_size,
                              hipStream_t stream) {
  (void)in_sizes; (void)n_in; (void)out_size; (void)ws_size;
  const float* hidden = (const float*)d_in[0];
  const float* emb    = (const float*)d_in[1];
  const int*   toks   = (const int*)d_in[2];
  const float* pres   = (const float*)d_in[3];
  const float* freq   = (const float*)d_in[4];
  const float* temp   = (const float*)d_in[5];
  const float* topp   = (const float*)d_in[6];
  const int*   topk   = (const int*)d_in[7];
  float* out = (float*)d_out;

  // ws layout: A3 (64*16384 = 1,048,576 B) + rowmax (1,024 B, zeroed)
  const size_t offA3 = 0;
  const size_t offRM = 1048576;

  _Float16* A3 = (_Float16*)((char*)d_ws + offA3);
  unsigned* rowmax = (unsigned*)((char*)d_ws + offRM);

  hipFuncSetAttribute((const void*)sample_row,
                      hipFuncAttributeMaxDynamicSharedMemorySize, SMEM_BYTES);

  hipMemsetAsync((char*)d_ws + offRM, 0, 1024, stream);
  convert_A<<<256, 256, 0, stream>>>(hidden, A3);
  gemm_f16s<<<NGBLK, 256, 0, stream>>>(emb, A3, temp, rowmax, out);
  sample_row<<<NB, 1024, SMEM_BYTES, stream>>>(out, rowmax, toks, pres, freq,
                                               temp, topp, topk);
}